// Round 6
// baseline (5984.914 us; speedup 1.0000x reference)
//
#include <hip/hip_runtime.h>
#include <math.h>

constexpr int BB = 32;     // batch
constexpr int NN_ = 512;   // sequence length
constexpr int DIN = 256;
constexpr int DH = 128;
constexpr int NITER = 10;
constexpr long HSTR = (long)NN_ * DH;    // 65536
constexpr long SSTR = (long)NN_ * NN_;   // 262144
constexpr long LSTR = 512L * 512L;       // 262144

__device__ __forceinline__ unsigned f2mono(float f) {
    unsigned u = __float_as_uint(f);
    return (u & 0x80000000u) ? ~u : (u | 0x80000000u);
}
__device__ __forceinline__ float mono2f(unsigned u) {
    return __uint_as_float((u & 0x80000000u) ? (u & 0x7fffffffu) : ~u);
}

// ---------------------------------------------------------------------------
// 128x128 in-register block-GJ inversion (16 rank-8 stages), verified R2-R5.
// r[8][8] per thread (tx,ty). Wave-redundant 8x8 pivot inversion via __shfl.
// Branch-free uniform update via adjusted panels. Opens with __syncthreads()
// (callers may have pending reads of the aliased LDS). Panels double-buffered.
// ---------------------------------------------------------------------------
__device__ __forceinline__ float invert128(float r[8][8], int tid,
        float (*RowP)[8][132], float (*ColPT)[8][132], float (*Rnew)[8][132])
{
    int tx = tid & 15, ty = tid >> 4;
    int lane = tid & 63, w = tid >> 6;
    int li = lane >> 3, lj = lane & 7;
    float lacc = 0.f;
    __syncthreads();
    for (int s8 = 0; s8 < 16; ++s8) {
        int p = s8 & 1;
        if (ty == s8) {
            #pragma unroll
            for (int i = 0; i < 8; ++i)
                #pragma unroll
                for (int j = 0; j < 8; ++j)
                    RowP[p][i][tx * 8 + j] = r[i][j];
        }
        if (tx == s8) {
            float sub = (ty == s8) ? 1.f : 0.f;
            #pragma unroll
            for (int i = 0; i < 8; ++i)
                #pragma unroll
                for (int j = 0; j < 8; ++j)
                    ColPT[p][j][ty * 8 + i] = r[i][j] - ((i == j) ? sub : 0.f);
        }
        __syncthreads();
        // all waves: invert 8x8 pivot block via shuffles
        float d = RowP[p][li][s8 * 8 + lj];
        float prod = 1.f;
        #pragma unroll
        for (int s = 0; s < 8; ++s) {
            float pv = __shfl(d, s * 9);
            prod *= pv;
            float pinv = 1.0f / pv;
            float rv = __shfl(d, s * 8 + lj);
            float cv = __shfl(d, li * 8 + s);
            float nd;
            if (li == s && lj == s)  nd = pinv;
            else if (li == s)        nd = rv * pinv;
            else if (lj == s)        nd = -cv * pinv;
            else                     nd = d - cv * pinv * rv;
            d = nd;
        }
        lacc += logf(fabsf(prod));
        // Rnew = Dinv @ RowP; pivot-col slice overwritten with I + Dinv
        {
            int sr = li;
            int jq = w * 32 + lj * 4;
            float dsr[8];
            #pragma unroll
            for (int t = 0; t < 8; ++t) dsr[t] = __shfl(d, (lane & 56) + t);
            float a0 = 0.f, a1 = 0.f, a2 = 0.f, a3 = 0.f;
            #pragma unroll
            for (int t = 0; t < 8; ++t) {
                float4 rp = *(const float4*)&RowP[p][t][jq];
                a0 += dsr[t] * rp.x; a1 += dsr[t] * rp.y;
                a2 += dsr[t] * rp.z; a3 += dsr[t] * rp.w;
            }
            if ((jq >> 3) == s8) {
                if ((jq & 7) == 0) {
                    a0 = dsr[0] + ((sr == 0) ? 1.f : 0.f);
                    a1 = dsr[1] + ((sr == 1) ? 1.f : 0.f);
                    a2 = dsr[2] + ((sr == 2) ? 1.f : 0.f);
                    a3 = dsr[3] + ((sr == 3) ? 1.f : 0.f);
                } else {
                    a0 = dsr[4] + ((sr == 4) ? 1.f : 0.f);
                    a1 = dsr[5] + ((sr == 5) ? 1.f : 0.f);
                    a2 = dsr[6] + ((sr == 6) ? 1.f : 0.f);
                    a3 = dsr[7] + ((sr == 7) ? 1.f : 0.f);
                }
            }
            *(float4*)&Rnew[p][sr][jq] = make_float4(a0, a1, a2, a3);
        }
        __syncthreads();
        // uniform branch-free update: r -= ColPT^T @ Rnew
        #pragma unroll
        for (int t = 0; t < 8; ++t) {
            float cp[8], rn[8];
            *(float4*)&cp[0] = *(const float4*)&ColPT[p][t][ty * 8];
            *(float4*)&cp[4] = *(const float4*)&ColPT[p][t][ty * 8 + 4];
            *(float4*)&rn[0] = *(const float4*)&Rnew[p][t][tx * 8];
            *(float4*)&rn[4] = *(const float4*)&Rnew[p][t][tx * 8 + 4];
            #pragma unroll
            for (int i = 0; i < 8; ++i)
                #pragma unroll
                for (int j = 0; j < 8; ++j)
                    r[i][j] -= cp[i] * rn[j];
        }
        // no trailing barrier: panels double-buffered
    }
    return lacc;
}

// ---------------------------------------------------------------------------
// Generic fp32 tiled GEMM (64x64 tile, BK=16, 4x4/thread), prefetched.
// ---------------------------------------------------------------------------
template<int AMODE, int BMODE, int EPI>
__global__ __launch_bounds__(256) void gemm64(
    const float* __restrict__ A, const float* __restrict__ Bm,
    float* __restrict__ C, const float* __restrict__ Dp, float* __restrict__ C2,
    int Mdim, int Ndim, int Kdim,
    long sA, long sB, long sC, long sD)
{
    constexpr int BK = 16;
    __shared__ float As[BK][64 + 4];
    __shared__ float Bs[BK][64 + 4];
    int b = blockIdx.z;
    const float* Ab = A + (long)b * sA;
    const float* Bb = Bm + (long)b * sB;
    int m0 = blockIdx.x * 64, n0 = blockIdx.y * 64;
    int tid = threadIdx.x;
    int tx = tid & 15, ty = tid >> 4;
    float acc[4][4] = {};

    int arow, acol, brow, bcol;
    if (AMODE == 0) { arow = tid >> 2; acol = (tid & 3) * 4; }
    else            { arow = tid >> 4; acol = (tid & 15) * 4; }
    if (BMODE == 0) { brow = tid >> 4; bcol = (tid & 15) * 4; }
    else            { brow = tid >> 2; bcol = (tid & 3) * 4; }

    float4 av, bv;
    if (AMODE == 0) av = *(const float4*)(Ab + (long)(m0 + arow) * Kdim + acol);
    else            av = *(const float4*)(Ab + (long)(0 + arow) * Mdim + m0 + acol);
    if (BMODE == 0) bv = *(const float4*)(Bb + (long)(0 + brow) * Ndim + n0 + bcol);
    else            bv = *(const float4*)(Bb + (long)(n0 + brow) * Kdim + bcol);

    for (int k0 = 0; k0 < Kdim; k0 += BK) {
        __syncthreads();
        if (AMODE == 0) {
            As[acol + 0][arow] = av.x; As[acol + 1][arow] = av.y;
            As[acol + 2][arow] = av.z; As[acol + 3][arow] = av.w;
        } else {
            *(float4*)&As[arow][acol] = av;
        }
        if (BMODE == 0) {
            *(float4*)&Bs[brow][bcol] = bv;
        } else {
            Bs[bcol + 0][brow] = bv.x; Bs[bcol + 1][brow] = bv.y;
            Bs[bcol + 2][brow] = bv.z; Bs[bcol + 3][brow] = bv.w;
        }
        float4 av2, bv2;
        if (k0 + BK < Kdim) {
            int k1 = k0 + BK;
            if (AMODE == 0) av2 = *(const float4*)(Ab + (long)(m0 + arow) * Kdim + k1 + acol);
            else            av2 = *(const float4*)(Ab + (long)(k1 + arow) * Mdim + m0 + acol);
            if (BMODE == 0) bv2 = *(const float4*)(Bb + (long)(k1 + brow) * Ndim + n0 + bcol);
            else            bv2 = *(const float4*)(Bb + (long)(n0 + brow) * Kdim + k1 + bcol);
        }
        __syncthreads();
        #pragma unroll
        for (int k = 0; k < BK; ++k) {
            float4 a4 = *(const float4*)&As[k][ty * 4];
            float4 b4 = *(const float4*)&Bs[k][tx * 4];
            float avv[4] = {a4.x, a4.y, a4.z, a4.w};
            float bvv[4] = {b4.x, b4.y, b4.z, b4.w};
            #pragma unroll
            for (int i = 0; i < 4; ++i)
                #pragma unroll
                for (int j = 0; j < 4; ++j)
                    acc[i][j] += avv[i] * bvv[j];
        }
        av = av2; bv = bv2;
    }

    int r0 = m0 + ty * 4, c0 = n0 + tx * 4;
    if (EPI == 0) {
        float* Cb = C + (long)b * sC;
        #pragma unroll
        for (int i = 0; i < 4; ++i)
            *(float4*)(Cb + (long)(r0 + i) * Ndim + c0) =
                make_float4(acc[i][0], acc[i][1], acc[i][2], acc[i][3]);
    } else if (EPI == 1) {
        float4 bias = *(const float4*)(Dp + c0);
        float bb4[4] = {bias.x, bias.y, bias.z, bias.w};
        #pragma unroll
        for (int i = 0; i < 4; ++i) {
            float pre[4];
            #pragma unroll
            for (int j = 0; j < 4; ++j) pre[j] = acc[i][j] + bb4[j];
            *(float4*)(C2 + (long)(r0 + i) * Ndim + c0) =
                make_float4(pre[0], pre[1], pre[2], pre[3]);
            *(float4*)(C + (long)(r0 + i) * Ndim + c0) =
                make_float4(fmaxf(pre[0], 0.f), fmaxf(pre[1], 0.f),
                            fmaxf(pre[2], 0.f), fmaxf(pre[3], 0.f));
        }
    } else {
        const float* Db = Dp + (long)b * sD;
        float* Cb = C + (long)b * sC;
        #pragma unroll
        for (int i = 0; i < 4; ++i) {
            float4 d = *(const float4*)(Db + (long)(r0 + i) * Ndim + c0);
            float pre[4] = {acc[i][0] + d.x, acc[i][1] + d.y,
                            acc[i][2] + d.z, acc[i][3] + d.w};
            *(float4*)(Cb + (long)(r0 + i) * Ndim + c0) =
                make_float4(fmaxf(pre[0], 0.f), fmaxf(pre[1], 0.f),
                            fmaxf(pre[2], 0.f), fmaxf(pre[3], 0.f));
        }
    }
}

// ---------------------------------------------------------------------------
// Scores GEMM with fused masked-max epilogue (128x128 tile, 8x8/thr).
// ---------------------------------------------------------------------------
__global__ __launch_bounds__(256) void score_gemm(
    const float* __restrict__ A, const float* __restrict__ Bm,
    float* __restrict__ C, const int* __restrict__ len,
    unsigned* __restrict__ cu)
{
    int b = blockIdx.z;
    const float* Ab = A + (long)b * HSTR;
    const float* Bb = Bm + (long)b * HSTR;
    int m0 = blockIdx.x * 128, n0 = blockIdx.y * 128;
    int tid = threadIdx.x, tx = tid & 15, ty = tid >> 4;
    __shared__ float As[8][132];
    __shared__ float Bs[8][132];
    float acc[8][8] = {};
    int row = tid >> 1, kq = (tid & 1) << 2;
    float4 av = *(const float4*)(Ab + (long)(m0 + row) * DH + kq);
    float4 bv = *(const float4*)(Bb + (long)(n0 + row) * DH + kq);
    for (int kc = 0; kc < DH; kc += 8) {
        __syncthreads();
        As[kq + 0][row] = av.x; As[kq + 1][row] = av.y;
        As[kq + 2][row] = av.z; As[kq + 3][row] = av.w;
        Bs[kq + 0][row] = bv.x; Bs[kq + 1][row] = bv.y;
        Bs[kq + 2][row] = bv.z; Bs[kq + 3][row] = bv.w;
        float4 av2, bv2;
        if (kc + 8 < DH) {
            av2 = *(const float4*)(Ab + (long)(m0 + row) * DH + kc + 8 + kq);
            bv2 = *(const float4*)(Bb + (long)(n0 + row) * DH + kc + 8 + kq);
        }
        __syncthreads();
        #pragma unroll
        for (int k = 0; k < 8; ++k) {
            float a[8], bb[8];
            *(float4*)&a[0] = *(float4*)&As[k][ty * 8];
            *(float4*)&a[4] = *(float4*)&As[k][ty * 8 + 4];
            *(float4*)&bb[0] = *(float4*)&Bs[k][tx * 8];
            *(float4*)&bb[4] = *(float4*)&Bs[k][tx * 8 + 4];
            #pragma unroll
            for (int i = 0; i < 8; ++i)
                #pragma unroll
                for (int j = 0; j < 8; ++j) acc[i][j] += a[i] * bb[j];
        }
        av = av2; bv = bv2;
    }
    int L = len[b];
    float vmax = -3.0e38f;
    float* Cb = C + (long)b * SSTR;
    #pragma unroll
    for (int i = 0; i < 8; ++i) {
        int h = m0 + ty * 8 + i;
        bool hok = (h <= L);
        *(float4*)(Cb + (long)h * NN_ + n0 + tx * 8) =
            make_float4(acc[i][0], acc[i][1], acc[i][2], acc[i][3]);
        *(float4*)(Cb + (long)h * NN_ + n0 + tx * 8 + 4) =
            make_float4(acc[i][4], acc[i][5], acc[i][6], acc[i][7]);
        #pragma unroll
        for (int j = 0; j < 8; ++j) {
            int m = n0 + tx * 8 + j;
            if (hok && m >= 1 && m <= L && m != h) vmax = fmaxf(vmax, acc[i][j]);
        }
    }
    __syncthreads();
    float* red = &As[0][0];
    red[tid] = vmax; __syncthreads();
    for (int off = 128; off; off >>= 1) {
        if (tid < off) red[tid] = fmaxf(red[tid], red[tid + off]);
        __syncthreads();
    }
    if (tid == 0) atomicMax(&cu[b], f2mono(red[0]));
}

// --------------------------- small helpers ---------------------------------
__global__ void zero_scal(float* scal) {
    if (threadIdx.x < 96) scal[threadIdx.x] = 0.f;
}

// ---------------------------------------------------------------------------
// Column sums (blocks y=0..7) + FUSED diag-0 build+invert (block y==8).
// The diag block is self-contained: computes its own colsums for tm=1..128,
// builds the (0,0) 128x128 Lhat block in registers, inverts it, writes
// Lm(0,0) and logdet. The 256 regular blocks run concurrently on other CUs,
// hiding the serial inversion.
// ---------------------------------------------------------------------------
__global__ __launch_bounds__(256) void colsum_k(const float* __restrict__ sc,
                                                const int* __restrict__ len,
                                                const unsigned* __restrict__ cu,
                                                float* __restrict__ colsum,
                                                float* __restrict__ Lm,
                                                float* __restrict__ logdet)
{
    __shared__ float sm[6][8][132];        // panels for invert / scratch
    int b = blockIdx.x, yb = blockIdx.y;   // (32, 9)
    int tid = threadIdx.x;
    int L = len[b];
    float c = mono2f(cu[b]);
    const float* S = sc + (long)b * SSTR;

    if (yb < 8) {
        int lane = tid & 63, w = tid >> 6;
        int m = yb * 64 + lane;
        float s = 0.f;
        bool mv = (m >= 1 && m <= L);
        if (mv) {
            for (int h = 1 + w; h < NN_; h += 4) {
                if (h <= L && h != m) s += expf(S[(long)h * NN_ + m] - c);
            }
        }
        float* part = &sm[0][0][0];        // [4][64]
        part[w * 64 + lane] = s; __syncthreads();
        if (tid < 64)
            colsum[(long)b * NN_ + yb * 64 + tid] =
                part[tid] + part[64 + tid] + part[128 + tid] + part[192 + tid];
        return;
    }

    // yb == 8: fused diag-0.  Phase A: private colsums for tm = 1..128.
    float* ph  = &sm[0][0][0];             // [2][128]
    float* csl = ph + 256;                 // [128]
    {
        int c2 = tid & 127, half = tid >> 7;
        int tm = c2 + 1;
        float s = 0.f;
        if (tm <= L) {
            int h0 = half * 256;
            for (int h = h0; h < h0 + 256; ++h) {
                if (h >= 1 && h <= L && h != tm)
                    s += expf(S[(long)h * NN_ + tm] - c);
            }
        }
        ph[half * 128 + c2] = s;
    }
    __syncthreads();
    if (tid < 128) csl[tid] = ph[tid] + ph[128 + tid];
    __syncthreads();
    // Phase B: build r[8][8] for the (0,0) block, then invert.
    int tx = tid & 15, ty = tid >> 4;
    float r[8][8];
    #pragma unroll
    for (int i = 0; i < 8; ++i) {
        int gi = ty * 8 + i;
        #pragma unroll
        for (int j = 0; j < 8; ++j) {
            int gj = tx * 8 + j;
            int tm = gj + 1;
            bool mv = (tm <= L);
            float v;
            if (gi == 0) {
                v = mv ? expf(S[tm] - c) : 0.f;
            } else if (gi == gj) {
                float rv = mv ? expf(S[tm] - c) : 0.f;
                v = rv + csl[gj] + (mv ? 0.f : 1.f);
            } else {
                int h = gi + 1;
                v = (h <= L && mv) ? -expf(S[(long)h * NN_ + tm] - c) : 0.f;
            }
            r[i][j] = v;
        }
    }
    // invert128 opens with __syncthreads(): csl reads above are safe.
    float lacc = invert128(r, tid,
                           (float(*)[8][132])&sm[0],
                           (float(*)[8][132])&sm[2],
                           (float(*)[8][132])&sm[4]);
    float* Ab = Lm + (long)b * LSTR;
    #pragma unroll
    for (int i = 0; i < 8; ++i) {
        *(float4*)(Ab + (long)(ty * 8 + i) * 512 + tx * 8) =
            make_float4(r[i][0], r[i][1], r[i][2], r[i][3]);
        *(float4*)(Ab + (long)(ty * 8 + i) * 512 + tx * 8 + 4) =
            make_float4(r[i][4], r[i][5], r[i][6], r[i][7]);
    }
    if (tid == 0) atomicAdd(&logdet[b], lacc);
}

// Lean row build: padded 512x512 Lhat EXCEPT the (0,0) 128x128 block (owned
// by colsum_k's diag block). No LDS, high occupancy. Emits column-panel 0
// rows 128..511 to Fb0.
__global__ __launch_bounds__(256) void build_rows(const float* __restrict__ sc,
                                                  const int* __restrict__ len,
                                                  const unsigned* __restrict__ cu,
                                                  const float* __restrict__ colsum,
                                                  float* __restrict__ Lm,
                                                  float* __restrict__ Fb0)
{
    int b = blockIdx.x, i = blockIdx.y;    // (32, 512)
    int tid = threadIdx.x;
    int L = len[b];
    float c = mono2f(cu[b]);
    const float* S = sc + (long)b * SSTR;
    const float* cs = colsum + (long)b * NN_;
    float* Lrow = Lm + (long)b * LSTR + (long)i * 512;
    float* Frow = Fb0 + (long)b * HSTR + (long)i * 128;
    #pragma unroll
    for (int q = 0; q < 2; ++q) {
        int j = tid + q * 256;
        float v;
        if (i == 511 || j == 511) {
            v = (i == j) ? 1.f : 0.f;
        } else {
            int tm = j + 1;
            bool mv = (tm <= L);
            if (i == 0) {
                v = mv ? expf(S[tm] - c) : 0.f;
            } else if (i == j) {
                float rv = mv ? expf(S[tm] - c) : 0.f;
                v = rv + cs[tm] + ((tm > L) ? 1.f : 0.f);
            } else {
                int h = i + 1;
                v = (h <= L && mv) ? -expf(S[(long)h * NN_ + tm] - c) : 0.f;
            }
        }
        if (!(i < 128 && j < 128)) Lrow[j] = v;
        if (q == 0 && j < 128 && i >= 128) Frow[j] = v;
    }
}

// Pivot-row panels: R_j = Dinv @ A[kb][jt] in place (3 blocks, jt != kb).
// Dual-writes R_j into next kb's Fbuf when jt == kb+1. Prefetched loads.
__global__ __launch_bounds__(256) void gj_panel(float* __restrict__ Lm,
                                                float* __restrict__ Fnext, int kb)
{
    int b = blockIdx.x, j = blockIdx.y;
    int jt = j + (j >= kb);
    int tid = threadIdx.x;
    float* base = Lm + (long)b * LSTR;
    const float* D = base + (long)(kb * 128) * 512 + kb * 128;
    float* Aj = base + (long)(kb * 128) * 512 + jt * 128;
    __shared__ float Ds_[8][132];
    __shared__ float Asj[8][132];
    int tx = tid & 15, ty = tid >> 4;
    int drow = tid >> 1, dkq = (tid & 1) << 2;
    int akr = tid >> 5, acq = (tid & 31) << 2;
    float acc[8][8] = {};
    float4 dv = *(const float4*)(D + (long)drow * 512 + dkq);
    float4 ajv = *(const float4*)(Aj + (long)akr * 512 + acq);
    for (int kc = 0; kc < 128; kc += 8) {
        __syncthreads();
        Ds_[dkq + 0][drow] = dv.x; Ds_[dkq + 1][drow] = dv.y;
        Ds_[dkq + 2][drow] = dv.z; Ds_[dkq + 3][drow] = dv.w;
        *(float4*)&Asj[akr][acq] = ajv;
        float4 dv2, ajv2;
        if (kc + 8 < 128) {
            dv2 = *(const float4*)(D + (long)drow * 512 + kc + 8 + dkq);
            ajv2 = *(const float4*)(Aj + (long)(kc + 8 + akr) * 512 + acq);
        }
        __syncthreads();
        #pragma unroll
        for (int k = 0; k < 8; ++k) {
            float a[8], bv[8];
            *(float4*)&a[0] = *(float4*)&Ds_[k][ty * 8];
            *(float4*)&a[4] = *(float4*)&Ds_[k][ty * 8 + 4];
            *(float4*)&bv[0] = *(float4*)&Asj[k][tx * 8];
            *(float4*)&bv[4] = *(float4*)&Asj[k][tx * 8 + 4];
            #pragma unroll
            for (int i = 0; i < 8; ++i)
                #pragma unroll
                for (int jj = 0; jj < 8; ++jj) acc[i][jj] += a[i] * bv[jj];
        }
        dv = dv2; ajv = ajv2;
    }
    bool dual = (jt == kb + 1);
    float* Fn = Fnext + (long)b * HSTR + (long)(kb * 128) * 128;
    #pragma unroll
    for (int i = 0; i < 8; ++i) {
        float4 o0 = make_float4(acc[i][0], acc[i][1], acc[i][2], acc[i][3]);
        float4 o1 = make_float4(acc[i][4], acc[i][5], acc[i][6], acc[i][7]);
        *(float4*)(Aj + (long)(ty * 8 + i) * 512 + tx * 8) = o0;
        *(float4*)(Aj + (long)(ty * 8 + i) * 512 + tx * 8 + 4) = o1;
        if (dual) {
            *(float4*)(Fn + (long)(ty * 8 + i) * 128 + tx * 8) = o0;
            *(float4*)(Fn + (long)(ty * 8 + i) * 128 + tx * 8 + 4) = o1;
        }
    }
}

// Trailing update: A[i][j] -= F_i @ R_j (j==kb: A[i][kb] = -F_i @ D).
// Dual-writes column kb+1 into Fnext. FUSE: the block computing trailing tile
// (kb+1,kb+1) continues into the in-register inversion of that tile.
template<int FUSE>
__global__ __launch_bounds__(256) void gj_update(float* __restrict__ Lm,
                                                 const float* __restrict__ Fbuf,
                                                 float* __restrict__ Fnext,
                                                 float* __restrict__ logdet, int kb)
{
    __shared__ float sm[FUSE ? 6 : 2][8][132];
    int b = blockIdx.x;
    int it = blockIdx.y;   // 0..2
    int jt = blockIdx.z;   // 0..3
    int ib = it + (it >= kb);
    int tid = threadIdx.x, tx = tid & 15, ty = tid >> 4;
    float* base = Lm + (long)b * LSTR;
    const float* F = Fbuf + (long)b * HSTR + (long)(ib * 128) * 128;
    const float* R = base + (long)(kb * 128) * 512 + jt * 128;
    float* Cb = base + (long)(ib * 128) * 512 + jt * 128;
    float (*Fs)[132] = sm[0];
    float (*Rs)[132] = sm[1];
    int frow = tid >> 1, fkq = (tid & 1) << 2;
    int rkr = tid >> 5, rcq = (tid & 31) << 2;
    float acc[8][8] = {};
    float4 fv = *(const float4*)(F + (long)frow * 128 + fkq);
    float4 rv = *(const float4*)(R + (long)rkr * 512 + rcq);
    for (int kc = 0; kc < 128; kc += 8) {
        __syncthreads();
        Fs[fkq + 0][frow] = fv.x; Fs[fkq + 1][frow] = fv.y;
        Fs[fkq + 2][frow] = fv.z; Fs[fkq + 3][frow] = fv.w;
        *(float4*)&Rs[rkr][rcq] = rv;
        float4 fv2, rv2;
        if (kc + 8 < 128) {
            fv2 = *(const float4*)(F + (long)frow * 128 + kc + 8 + fkq);
            rv2 = *(const float4*)(R + (long)(kc + 8 + rkr) * 512 + rcq);
        }
        __syncthreads();
        #pragma unroll
        for (int k = 0; k < 8; ++k) {
            float a[8], bv[8];
            *(float4*)&a[0] = *(float4*)&Fs[k][ty * 8];
            *(float4*)&a[4] = *(float4*)&Fs[k][ty * 8 + 4];
            *(float4*)&bv[0] = *(float4*)&Rs[k][tx * 8];
            *(float4*)&bv[4] = *(float4*)&Rs[k][tx * 8 + 4];
            #pragma unroll
            for (int i = 0; i < 8; ++i)
                #pragma unroll
                for (int j = 0; j < 8; ++j) acc[i][j] += a[i] * bv[j];
        }
        fv = fv2; rv = rv2;
    }
    if (FUSE && ib == kb + 1 && jt == kb + 1) {
        #pragma unroll
        for (int i = 0; i < 8; ++i) {
            float4 o0 = *(const float4*)(Cb + (long)(ty * 8 + i) * 512 + tx * 8);
            float4 o1 = *(const float4*)(Cb + (long)(ty * 8 + i) * 512 + tx * 8 + 4);
            acc[i][0] = o0.x - acc[i][0]; acc[i][1] = o0.y - acc[i][1];
            acc[i][2] = o0.z - acc[i][2]; acc[i][3] = o0.w - acc[i][3];
            acc[i][4] = o1.x - acc[i][4]; acc[i][5] = o1.y - acc[i][5];
            acc[i][6] = o1.z - acc[i][6]; acc[i][7] = o1.w - acc[i][7];
        }
        float lacc = invert128(acc, tid,
                               (float(*)[8][132])&sm[0],
                               (float(*)[8][132])&sm[FUSE ? 2 : 0],
                               (float(*)[8][132])&sm[FUSE ? 4 : 0]);
        #pragma unroll
        for (int i = 0; i < 8; ++i) {
            *(float4*)(Cb + (long)(ty * 8 + i) * 512 + tx * 8) =
                make_float4(acc[i][0], acc[i][1], acc[i][2], acc[i][3]);
            *(float4*)(Cb + (long)(ty * 8 + i) * 512 + tx * 8 + 4) =
                make_float4(acc[i][4], acc[i][5], acc[i][6], acc[i][7]);
        }
        if (tid == 0) atomicAdd(&logdet[b], lacc);
        return;
    }
    bool dual = (jt == kb + 1);
    float* Fn = Fnext + (long)b * HSTR + (long)(ib * 128) * 128;
    if (jt == kb) {
        #pragma unroll
        for (int i = 0; i < 8; ++i) {
            *(float4*)(Cb + (long)(ty * 8 + i) * 512 + tx * 8) =
                make_float4(-acc[i][0], -acc[i][1], -acc[i][2], -acc[i][3]);
            *(float4*)(Cb + (long)(ty * 8 + i) * 512 + tx * 8 + 4) =
                make_float4(-acc[i][4], -acc[i][5], -acc[i][6], -acc[i][7]);
        }
    } else {
        #pragma unroll
        for (int i = 0; i < 8; ++i) {
            float4 o0 = *(const float4*)(Cb + (long)(ty * 8 + i) * 512 + tx * 8);
            float4 o1 = *(const float4*)(Cb + (long)(ty * 8 + i) * 512 + tx * 8 + 4);
            o0 = make_float4(o0.x - acc[i][0], o0.y - acc[i][1],
                             o0.z - acc[i][2], o0.w - acc[i][3]);
            o1 = make_float4(o1.x - acc[i][4], o1.y - acc[i][5],
                             o1.z - acc[i][6], o1.w - acc[i][7]);
            *(float4*)(Cb + (long)(ty * 8 + i) * 512 + tx * 8) = o0;
            *(float4*)(Cb + (long)(ty * 8 + i) * 512 + tx * 8 + 4) = o1;
            if (dual) {
                *(float4*)(Fn + (long)(ty * 8 + i) * 128 + tx * 8) = o0;
                *(float4*)(Fn + (long)(ty * 8 + i) * 128 + tx * 8 + 4) = o1;
            }
        }
    }
}

// --------------------------- marginals Y + entropy partials -----------------
__global__ __launch_bounds__(256) void y_k(const float* __restrict__ sc,
                                           const float* __restrict__ Binv,
                                           const int* __restrict__ len,
                                           const unsigned* __restrict__ cu,
                                           float* __restrict__ Y,
                                           float* __restrict__ Ssum)
{
    int b = blockIdx.x;
    int ht = blockIdx.y >> 3, mt = blockIdx.y & 7;
    int h0 = ht * 64, m0 = mt * 64;
    int tid = threadIdx.x;
    int L = len[b];
    float c = mono2f(cu[b]);
    const float* S = sc + (long)b * SSTR;
    const float* Bi = Binv + (long)b * LSTR;
    float* Yb = Y + (long)b * SSTR;
    __shared__ float Bs[64][65];
    __shared__ float Ds[64], C0s[64];
    {
        int hh = tid & 63, m4 = tid >> 6;
        int col = h0 + hh - 1;
        for (int mm = m4; mm < 64; mm += 4) {
            int row = m0 + mm - 1;
            Bs[mm][hh] = (row >= 0 && col >= 0) ? Bi[(long)row * 512 + col] : 0.f;
        }
    }
    if (tid < 64) {
        int row = m0 + tid - 1;
        Ds[tid] = (row >= 0) ? Bi[(long)row * 512 + row] : 0.f;
    } else if (tid < 128) {
        int mm = tid - 64, row = m0 + mm - 1;
        C0s[mm] = (row >= 0) ? Bi[(long)row * 512] : 0.f;
    }
    __syncthreads();
    int mm = tid & 63, hq = tid >> 6;
    int m = m0 + mm;
    float lsum = 0.f;
    bool mvalid = (m >= 1 && m <= L);
    float dterm = (m >= 2) ? Ds[mm] : 0.f;
    #pragma unroll
    for (int hi = 0; hi < 16; ++hi) {
        int hh = hq * 16 + hi;
        int h = h0 + hh;
        float s = S[(long)h * NN_ + m];
        float y = 0.f;
        if (mvalid && h <= L && h != m) {
            float a = expf(s - c);
            float g;
            if (h == 0) g = C0s[mm] + dterm;
            else g = dterm - ((h >= 2) ? Bs[mm][hh] : 0.f);
            y = a * g;
        }
        Yb[(long)h * NN_ + m] = y;
        lsum += y * s;
    }
    __shared__ float red[256];
    red[tid] = lsum; __syncthreads();
    for (int off = 128; off; off >>= 1) {
        if (tid < off) red[tid] += red[tid + off];
        __syncthreads();
    }
    if (tid == 0) atomicAdd(&Ssum[b], red[0]);
}

// finalize + re-zero accumulators for the next iteration
__global__ void fin_k(const int* __restrict__ len, unsigned* __restrict__ cu,
                      float* __restrict__ logdet, float* __restrict__ Ssum,
                      float* __restrict__ outLogZ, float* __restrict__ outEntr)
{
    int b = threadIdx.x;
    if (b < 32) {
        float c = mono2f(cu[b]);
        float lz = logdet[b] + (float)len[b] * c;
        outLogZ[b] = lz;
        outEntr[b] = lz - Ssum[b];
        cu[b] = 0u;
        logdet[b] = 0.f;
        Ssum[b] = 0.f;
    }
}

// ---------------------------------------------------------------------------
extern "C" void kernel_launch(void* const* d_in, const int* in_sizes, int n_in,
                              void* d_out, int out_size, void* d_ws, size_t ws_size,
                              hipStream_t stream)
{
    const float* Xh = (const float*)d_in[0];
    const float* Xm = (const float*)d_in[1];
    const int*   len = (const int*)d_in[2];
    const float* Wh = (const float*)d_in[3];
    const float* bh = (const float*)d_in[4];
    const float* Wm = (const float*)d_in[5];
    const float* bm = (const float*)d_in[6];
    const float* V  = (const float*)d_in[7];

    float* ws = (float*)d_ws;
    constexpr long U = 2097152;           // 32*512*128
    float* H0 = ws;
    float* M0 = ws + U;
    float* Ha = ws + 2 * U;
    float* Ma = ws + 3 * U;
    float* Hb = ws + 4 * U;
    float* Mb = ws + 5 * U;
    float* T1 = ws + 6 * U;               // P = H@V (live across GJ!)
    float* Yt = ws + 7 * U;               // Q scratch (feedback) / Fbuf ping (GJ)
    float* Lm = ws + 8 * U;               // 32 x 512 x 512
    float* cs = ws + 12 * U;              // colsum 32*512
    float* scal = ws + 12 * U + 16384;    // c_u[32] | logdet[32] | Ssum[32]
    unsigned* cu = (unsigned*)scal;
    float* logdet = scal + 32;
    float* Ssum = scal + 64;

    float* Sout = (float*)d_out;                        // scores  [32,512,512]
    float* outLogZ = (float*)d_out + 8388608;           // logZ    [32]
    float* Yout = (float*)d_out + 8388640;              // Y       [32,512,512]
    float* outEntr = (float*)d_out + 8388640 + 8388608; // entr    [32]

    zero_scal<<<1, 96, 0, stream>>>(scal);

    // H0 = Xh@Wh^T + bh ; H = relu(H0)   (and same for M)
    gemm64<0,1,1><<<dim3(256, 2, 1), 256, 0, stream>>>(
        Xh, Wh, Ha, bh, H0, 16384, DH, DIN, 0, 0, 0, 0);
    gemm64<0,1,1><<<dim3(256, 2, 1), 256, 0, stream>>>(
        Xm, Wm, Ma, bm, M0, 16384, DH, DIN, 0, 0, 0, 0);

    float* Hc = Ha; float* Mc = Ma; float* Hn = Hb; float* Mn = Mb;
    for (int t = 0; t < NITER; ++t) {
        if (t > 0) {
            // Q = Mc @ V^T (Yt); Hn = relu(H0 + Y@Q); Mn = relu(M0 + Y^T@P)
            gemm64<0,1,0><<<dim3(8,2,BB),256,0,stream>>>(
                Mc, V, Yt, nullptr, nullptr, 512, DH, DH, HSTR, 0, HSTR, 0);
            gemm64<0,0,2><<<dim3(8,2,BB),256,0,stream>>>(
                Yout, Yt, Hn, H0, nullptr, 512, DH, 512, SSTR, HSTR, HSTR, HSTR);
            gemm64<1,0,2><<<dim3(8,2,BB),256,0,stream>>>(
                Yout, T1, Mn, M0, nullptr, 512, DH, 512, SSTR, HSTR, HSTR, HSTR);
            { float* tmp = Hc; Hc = Hn; Hn = tmp; }
            { float* tmp = Mc; Mc = Mn; Mn = tmp; }
        }
        // P = Hc @ V (T1, persists to next feedback); scores = P @ Mc^T
        gemm64<0,0,0><<<dim3(8,2,BB),256,0,stream>>>(
            Hc, V, T1, nullptr, nullptr, 512, DH, DH, HSTR, 0, HSTR, 0);
        score_gemm<<<dim3(4,4,BB),256,0,stream>>>(T1, Mc, Sout, len, cu);

        // colsum (+ fused diag-0 inversion), then lean row build
        colsum_k<<<dim3(BB,9),256,0,stream>>>(Sout, len, cu, cs, Lm, logdet);
        build_rows<<<dim3(BB,512),256,0,stream>>>(Sout, len, cu, cs, Lm, Yt);

        // Fbuf ping-pong: even kb reads Yt, writes Hn (dead during GJ); odd flips
        float* Fbufs[2] = {Yt, Hn};
        for (int kb = 0; kb < 4; ++kb) {
            float* Fcur  = Fbufs[kb & 1];
            float* Fnext = Fbufs[(kb + 1) & 1];
            gj_panel<<<dim3(BB,3),256,0,stream>>>(Lm, Fnext, kb);
            if (kb < 3)
                gj_update<1><<<dim3(BB,3,4),256,0,stream>>>(Lm, Fcur, Fnext, logdet, kb);
            else
                gj_update<0><<<dim3(BB,3,4),256,0,stream>>>(Lm, Fcur, Fnext, logdet, kb);
        }
        y_k<<<dim3(BB,64),256,0,stream>>>(Sout, Lm, len, cu, Yout, Ssum);
        fin_k<<<1,32,0,stream>>>(len, cu, logdet, Ssum, outLogZ, outEntr);
    }
}

// Round 7
// 5632.888 us; speedup vs baseline: 1.0625x; 1.0625x over previous
//
#include <hip/hip_runtime.h>
#include <math.h>

constexpr int BB = 32;     // batch
constexpr int NN_ = 512;   // sequence length
constexpr int DIN = 256;
constexpr int DH = 128;
constexpr int NITER = 10;
constexpr long HSTR = (long)NN_ * DH;    // 65536
constexpr long SSTR = (long)NN_ * NN_;   // 262144
constexpr long LSTR = 512L * 512L;       // 262144

__device__ __forceinline__ unsigned f2mono(float f) {
    unsigned u = __float_as_uint(f);
    return (u & 0x80000000u) ? ~u : (u | 0x80000000u);
}
__device__ __forceinline__ float mono2f(unsigned u) {
    return __uint_as_float((u & 0x80000000u) ? (u & 0x7fffffffu) : ~u);
}

// ---------------------------------------------------------------------------
// 128x128 in-register block-GJ inversion (16 rank-8 stages), verified R2-R6.
// r[8][8] per thread (tx,ty). Wave-redundant 8x8 pivot inversion via __shfl.
// Branch-free uniform update via adjusted panels. Opens with __syncthreads().
// ---------------------------------------------------------------------------
__device__ __forceinline__ float invert128(float r[8][8], int tid,
        float (*RowP)[8][132], float (*ColPT)[8][132], float (*Rnew)[8][132])
{
    int tx = tid & 15, ty = tid >> 4;
    int lane = tid & 63, w = tid >> 6;
    int li = lane >> 3, lj = lane & 7;
    float lacc = 0.f;
    __syncthreads();
    for (int s8 = 0; s8 < 16; ++s8) {
        int p = s8 & 1;
        if (ty == s8) {
            #pragma unroll
            for (int i = 0; i < 8; ++i)
                #pragma unroll
                for (int j = 0; j < 8; ++j)
                    RowP[p][i][tx * 8 + j] = r[i][j];
        }
        if (tx == s8) {
            float sub = (ty == s8) ? 1.f : 0.f;
            #pragma unroll
            for (int i = 0; i < 8; ++i)
                #pragma unroll
                for (int j = 0; j < 8; ++j)
                    ColPT[p][j][ty * 8 + i] = r[i][j] - ((i == j) ? sub : 0.f);
        }
        __syncthreads();
        // all waves: invert 8x8 pivot block via shuffles
        float d = RowP[p][li][s8 * 8 + lj];
        float prod = 1.f;
        #pragma unroll
        for (int s = 0; s < 8; ++s) {
            float pv = __shfl(d, s * 9);
            prod *= pv;
            float pinv = 1.0f / pv;
            float rv = __shfl(d, s * 8 + lj);
            float cv = __shfl(d, li * 8 + s);
            float nd;
            if (li == s && lj == s)  nd = pinv;
            else if (li == s)        nd = rv * pinv;
            else if (lj == s)        nd = -cv * pinv;
            else                     nd = d - cv * pinv * rv;
            d = nd;
        }
        lacc += logf(fabsf(prod));
        // Rnew = Dinv @ RowP; pivot-col slice overwritten with I + Dinv
        {
            int sr = li;
            int jq = w * 32 + lj * 4;
            float dsr[8];
            #pragma unroll
            for (int t = 0; t < 8; ++t) dsr[t] = __shfl(d, (lane & 56) + t);
            float a0 = 0.f, a1 = 0.f, a2 = 0.f, a3 = 0.f;
            #pragma unroll
            for (int t = 0; t < 8; ++t) {
                float4 rp = *(const float4*)&RowP[p][t][jq];
                a0 += dsr[t] * rp.x; a1 += dsr[t] * rp.y;
                a2 += dsr[t] * rp.z; a3 += dsr[t] * rp.w;
            }
            if ((jq >> 3) == s8) {
                if ((jq & 7) == 0) {
                    a0 = dsr[0] + ((sr == 0) ? 1.f : 0.f);
                    a1 = dsr[1] + ((sr == 1) ? 1.f : 0.f);
                    a2 = dsr[2] + ((sr == 2) ? 1.f : 0.f);
                    a3 = dsr[3] + ((sr == 3) ? 1.f : 0.f);
                } else {
                    a0 = dsr[4] + ((sr == 4) ? 1.f : 0.f);
                    a1 = dsr[5] + ((sr == 5) ? 1.f : 0.f);
                    a2 = dsr[6] + ((sr == 6) ? 1.f : 0.f);
                    a3 = dsr[7] + ((sr == 7) ? 1.f : 0.f);
                }
            }
            *(float4*)&Rnew[p][sr][jq] = make_float4(a0, a1, a2, a3);
        }
        __syncthreads();
        // uniform branch-free update: r -= ColPT^T @ Rnew
        #pragma unroll
        for (int t = 0; t < 8; ++t) {
            float cp[8], rn[8];
            *(float4*)&cp[0] = *(const float4*)&ColPT[p][t][ty * 8];
            *(float4*)&cp[4] = *(const float4*)&ColPT[p][t][ty * 8 + 4];
            *(float4*)&rn[0] = *(const float4*)&Rnew[p][t][tx * 8];
            *(float4*)&rn[4] = *(const float4*)&Rnew[p][t][tx * 8 + 4];
            #pragma unroll
            for (int i = 0; i < 8; ++i)
                #pragma unroll
                for (int j = 0; j < 8; ++j)
                    r[i][j] -= cp[i] * rn[j];
        }
        // no trailing barrier: panels double-buffered
    }
    return lacc;
}

// ---------------------------------------------------------------------------
// Generic fp32 tiled GEMM (64x64 tile, BK=16, 4x4/thread), prefetched.
// ---------------------------------------------------------------------------
template<int AMODE, int BMODE, int EPI>
__global__ __launch_bounds__(256) void gemm64(
    const float* __restrict__ A, const float* __restrict__ Bm,
    float* __restrict__ C, const float* __restrict__ Dp, float* __restrict__ C2,
    int Mdim, int Ndim, int Kdim,
    long sA, long sB, long sC, long sD)
{
    constexpr int BK = 16;
    __shared__ float As[BK][64 + 4];
    __shared__ float Bs[BK][64 + 4];
    int b = blockIdx.z;
    const float* Ab = A + (long)b * sA;
    const float* Bb = Bm + (long)b * sB;
    int m0 = blockIdx.x * 64, n0 = blockIdx.y * 64;
    int tid = threadIdx.x;
    int tx = tid & 15, ty = tid >> 4;
    float acc[4][4] = {};

    int arow, acol, brow, bcol;
    if (AMODE == 0) { arow = tid >> 2; acol = (tid & 3) * 4; }
    else            { arow = tid >> 4; acol = (tid & 15) * 4; }
    if (BMODE == 0) { brow = tid >> 4; bcol = (tid & 15) * 4; }
    else            { brow = tid >> 2; bcol = (tid & 3) * 4; }

    float4 av, bv;
    if (AMODE == 0) av = *(const float4*)(Ab + (long)(m0 + arow) * Kdim + acol);
    else            av = *(const float4*)(Ab + (long)(0 + arow) * Mdim + m0 + acol);
    if (BMODE == 0) bv = *(const float4*)(Bb + (long)(0 + brow) * Ndim + n0 + bcol);
    else            bv = *(const float4*)(Bb + (long)(n0 + brow) * Kdim + bcol);

    for (int k0 = 0; k0 < Kdim; k0 += BK) {
        __syncthreads();
        if (AMODE == 0) {
            As[acol + 0][arow] = av.x; As[acol + 1][arow] = av.y;
            As[acol + 2][arow] = av.z; As[acol + 3][arow] = av.w;
        } else {
            *(float4*)&As[arow][acol] = av;
        }
        if (BMODE == 0) {
            *(float4*)&Bs[brow][bcol] = bv;
        } else {
            Bs[bcol + 0][brow] = bv.x; Bs[bcol + 1][brow] = bv.y;
            Bs[bcol + 2][brow] = bv.z; Bs[bcol + 3][brow] = bv.w;
        }
        float4 av2, bv2;
        if (k0 + BK < Kdim) {
            int k1 = k0 + BK;
            if (AMODE == 0) av2 = *(const float4*)(Ab + (long)(m0 + arow) * Kdim + k1 + acol);
            else            av2 = *(const float4*)(Ab + (long)(k1 + arow) * Mdim + m0 + acol);
            if (BMODE == 0) bv2 = *(const float4*)(Bb + (long)(k1 + brow) * Ndim + n0 + bcol);
            else            bv2 = *(const float4*)(Bb + (long)(n0 + brow) * Kdim + k1 + bcol);
        }
        __syncthreads();
        #pragma unroll
        for (int k = 0; k < BK; ++k) {
            float4 a4 = *(const float4*)&As[k][ty * 4];
            float4 b4 = *(const float4*)&Bs[k][tx * 4];
            float avv[4] = {a4.x, a4.y, a4.z, a4.w};
            float bvv[4] = {b4.x, b4.y, b4.z, b4.w};
            #pragma unroll
            for (int i = 0; i < 4; ++i)
                #pragma unroll
                for (int j = 0; j < 4; ++j)
                    acc[i][j] += avv[i] * bvv[j];
        }
        av = av2; bv = bv2;
    }

    int r0 = m0 + ty * 4, c0 = n0 + tx * 4;
    if (EPI == 0) {
        float* Cb = C + (long)b * sC;
        #pragma unroll
        for (int i = 0; i < 4; ++i)
            *(float4*)(Cb + (long)(r0 + i) * Ndim + c0) =
                make_float4(acc[i][0], acc[i][1], acc[i][2], acc[i][3]);
    } else if (EPI == 1) {
        float4 bias = *(const float4*)(Dp + c0);
        float bb4[4] = {bias.x, bias.y, bias.z, bias.w};
        #pragma unroll
        for (int i = 0; i < 4; ++i) {
            float pre[4];
            #pragma unroll
            for (int j = 0; j < 4; ++j) pre[j] = acc[i][j] + bb4[j];
            *(float4*)(C2 + (long)(r0 + i) * Ndim + c0) =
                make_float4(pre[0], pre[1], pre[2], pre[3]);
            *(float4*)(C + (long)(r0 + i) * Ndim + c0) =
                make_float4(fmaxf(pre[0], 0.f), fmaxf(pre[1], 0.f),
                            fmaxf(pre[2], 0.f), fmaxf(pre[3], 0.f));
        }
    } else {
        const float* Db = Dp + (long)b * sD;
        float* Cb = C + (long)b * sC;
        #pragma unroll
        for (int i = 0; i < 4; ++i) {
            float4 d = *(const float4*)(Db + (long)(r0 + i) * Ndim + c0);
            float pre[4] = {acc[i][0] + d.x, acc[i][1] + d.y,
                            acc[i][2] + d.z, acc[i][3] + d.w};
            *(float4*)(Cb + (long)(r0 + i) * Ndim + c0) =
                make_float4(fmaxf(pre[0], 0.f), fmaxf(pre[1], 0.f),
                            fmaxf(pre[2], 0.f), fmaxf(pre[3], 0.f));
        }
    }
}

// ---------------------------------------------------------------------------
// Scores GEMM with fused masked-max epilogue (128x128 tile, 8x8/thr).
// ---------------------------------------------------------------------------
__global__ __launch_bounds__(256) void score_gemm(
    const float* __restrict__ A, const float* __restrict__ Bm,
    float* __restrict__ C, const int* __restrict__ len,
    unsigned* __restrict__ cu)
{
    int b = blockIdx.z;
    const float* Ab = A + (long)b * HSTR;
    const float* Bb = Bm + (long)b * HSTR;
    int m0 = blockIdx.x * 128, n0 = blockIdx.y * 128;
    int tid = threadIdx.x, tx = tid & 15, ty = tid >> 4;
    __shared__ float As[8][132];
    __shared__ float Bs[8][132];
    float acc[8][8] = {};
    int row = tid >> 1, kq = (tid & 1) << 2;
    float4 av = *(const float4*)(Ab + (long)(m0 + row) * DH + kq);
    float4 bv = *(const float4*)(Bb + (long)(n0 + row) * DH + kq);
    for (int kc = 0; kc < DH; kc += 8) {
        __syncthreads();
        As[kq + 0][row] = av.x; As[kq + 1][row] = av.y;
        As[kq + 2][row] = av.z; As[kq + 3][row] = av.w;
        Bs[kq + 0][row] = bv.x; Bs[kq + 1][row] = bv.y;
        Bs[kq + 2][row] = bv.z; Bs[kq + 3][row] = bv.w;
        float4 av2, bv2;
        if (kc + 8 < DH) {
            av2 = *(const float4*)(Ab + (long)(m0 + row) * DH + kc + 8 + kq);
            bv2 = *(const float4*)(Bb + (long)(n0 + row) * DH + kc + 8 + kq);
        }
        __syncthreads();
        #pragma unroll
        for (int k = 0; k < 8; ++k) {
            float a[8], bb[8];
            *(float4*)&a[0] = *(float4*)&As[k][ty * 8];
            *(float4*)&a[4] = *(float4*)&As[k][ty * 8 + 4];
            *(float4*)&bb[0] = *(float4*)&Bs[k][tx * 8];
            *(float4*)&bb[4] = *(float4*)&Bs[k][tx * 8 + 4];
            #pragma unroll
            for (int i = 0; i < 8; ++i)
                #pragma unroll
                for (int j = 0; j < 8; ++j) acc[i][j] += a[i] * bb[j];
        }
        av = av2; bv = bv2;
    }
    int L = len[b];
    float vmax = -3.0e38f;
    float* Cb = C + (long)b * SSTR;
    #pragma unroll
    for (int i = 0; i < 8; ++i) {
        int h = m0 + ty * 8 + i;
        bool hok = (h <= L);
        *(float4*)(Cb + (long)h * NN_ + n0 + tx * 8) =
            make_float4(acc[i][0], acc[i][1], acc[i][2], acc[i][3]);
        *(float4*)(Cb + (long)h * NN_ + n0 + tx * 8 + 4) =
            make_float4(acc[i][4], acc[i][5], acc[i][6], acc[i][7]);
        #pragma unroll
        for (int j = 0; j < 8; ++j) {
            int m = n0 + tx * 8 + j;
            if (hok && m >= 1 && m <= L && m != h) vmax = fmaxf(vmax, acc[i][j]);
        }
    }
    __syncthreads();
    float* red = &As[0][0];
    red[tid] = vmax; __syncthreads();
    for (int off = 128; off; off >>= 1) {
        if (tid < off) red[tid] = fmaxf(red[tid], red[tid + off]);
        __syncthreads();
    }
    if (tid == 0) atomicMax(&cu[b], f2mono(red[0]));
}

// --------------------------- small helpers ---------------------------------
__global__ void zero_scal(float* scal) {
    if (threadIdx.x < 96) scal[threadIdx.x] = 0.f;
}

// Lean column sums (grid (32,8)) — low VGPR, tiny LDS, high occupancy.
__global__ __launch_bounds__(256) void colsum_k(const float* __restrict__ sc,
                                                const int* __restrict__ len,
                                                const unsigned* __restrict__ cu,
                                                float* __restrict__ colsum)
{
    int b = blockIdx.x, yb = blockIdx.y;   // (32, 8)
    int tid = threadIdx.x, lane = tid & 63, w = tid >> 6;
    int L = len[b];
    float c = mono2f(cu[b]);
    int m = yb * 64 + lane;
    const float* S = sc + (long)b * SSTR;
    float s = 0.f;
    bool mv = (m >= 1 && m <= L);
    if (mv) {
        for (int h = 1 + w; h < NN_; h += 4) {
            if (h <= L && h != m) s += expf(S[(long)h * NN_ + m] - c);
        }
    }
    __shared__ float part[4][64];
    part[w][lane] = s; __syncthreads();
    if (tid < 64)
        colsum[(long)b * NN_ + yb * 64 + tid] =
            part[0][tid] + part[1][tid] + part[2][tid] + part[3][tid];
}

// ---------------------------------------------------------------------------
// Build padded 512x512 Lhat + FUSED diag-0 inversion.
// blockIdx.y == 0 (dispatched FIRST): builds the (0,0) 128x128 block from
// scores + GLOBAL colsum (no redundant work), inverts in-register, writes
// Lm(0,0) + logdet. Runs concurrently with the 2048 row blocks.
// blockIdx.y >= 1: EIGHT rows per block (i = (y-1)*8 + r) — fat streaming
// blocks (16 KB read + 16 KB write each). Rows 0..127 skip cols 0..127.
// Emits column-panel 0 rows 128..511 to Fb0.
// ---------------------------------------------------------------------------
__global__ __launch_bounds__(256) void build_rows(const float* __restrict__ sc,
                                                  const int* __restrict__ len,
                                                  const unsigned* __restrict__ cu,
                                                  const float* __restrict__ colsum,
                                                  float* __restrict__ Lm,
                                                  float* __restrict__ Fb0,
                                                  float* __restrict__ logdet)
{
    __shared__ float sm[6][8][132];
    int b = blockIdx.x;
    int tid = threadIdx.x;
    int L = len[b];
    float c = mono2f(cu[b]);
    const float* S = sc + (long)b * SSTR;
    const float* cs = colsum + (long)b * NN_;

    if (blockIdx.y == 0) {
        // fused diag-0: build (0,0) block from S + global colsum, invert
        int tx = tid & 15, ty = tid >> 4;
        float r[8][8];
        #pragma unroll
        for (int i = 0; i < 8; ++i) {
            int gi = ty * 8 + i;
            #pragma unroll
            for (int j = 0; j < 8; ++j) {
                int gj = tx * 8 + j;
                int tm = gj + 1;
                bool mv = (tm <= L);
                float v;
                if (gi == 0) {
                    v = mv ? expf(S[tm] - c) : 0.f;
                } else if (gi == gj) {
                    float rv = mv ? expf(S[tm] - c) : 0.f;
                    v = rv + cs[tm] + (mv ? 0.f : 1.f);
                } else {
                    int h = gi + 1;
                    v = (h <= L && mv) ? -expf(S[(long)h * NN_ + tm] - c) : 0.f;
                }
                r[i][j] = v;
            }
        }
        float lacc = invert128(r, tid,
                               (float(*)[8][132])&sm[0],
                               (float(*)[8][132])&sm[2],
                               (float(*)[8][132])&sm[4]);
        float* Ab = Lm + (long)b * LSTR;
        #pragma unroll
        for (int i = 0; i < 8; ++i) {
            *(float4*)(Ab + (long)(ty * 8 + i) * 512 + tx * 8) =
                make_float4(r[i][0], r[i][1], r[i][2], r[i][3]);
            *(float4*)(Ab + (long)(ty * 8 + i) * 512 + tx * 8 + 4) =
                make_float4(r[i][4], r[i][5], r[i][6], r[i][7]);
        }
        if (tid == 0) atomicAdd(&logdet[b], lacc);
        return;
    }

    int i0 = (blockIdx.y - 1) * 8;
    #pragma unroll
    for (int r = 0; r < 8; ++r) {
        int i = i0 + r;
        float* Lrow = Lm + (long)b * LSTR + (long)i * 512;
        float* Frow = Fb0 + (long)b * HSTR + (long)i * 128;
        #pragma unroll
        for (int q = 0; q < 2; ++q) {
            int j = tid + q * 256;
            float v;
            if (i == 511 || j == 511) {
                v = (i == j) ? 1.f : 0.f;
            } else {
                int tm = j + 1;
                bool mv = (tm <= L);
                if (i == 0) {
                    v = mv ? expf(S[tm] - c) : 0.f;
                } else if (i == j) {
                    float rv = mv ? expf(S[tm] - c) : 0.f;
                    v = rv + cs[tm] + ((tm > L) ? 1.f : 0.f);
                } else {
                    int h = i + 1;
                    v = (h <= L && mv) ? -expf(S[(long)h * NN_ + tm] - c) : 0.f;
                }
            }
            if (!(i < 128 && j < 128)) Lrow[j] = v;
            if (q == 0 && j < 128 && i >= 128) Frow[j] = v;
        }
    }
}

// Pivot-row panels: R_j = Dinv @ A[kb][jt] in place (3 blocks, jt != kb).
// Dual-writes R_j into next kb's Fbuf when jt == kb+1. Prefetched loads.
__global__ __launch_bounds__(256) void gj_panel(float* __restrict__ Lm,
                                                float* __restrict__ Fnext, int kb)
{
    int b = blockIdx.x, j = blockIdx.y;
    int jt = j + (j >= kb);
    int tid = threadIdx.x;
    float* base = Lm + (long)b * LSTR;
    const float* D = base + (long)(kb * 128) * 512 + kb * 128;
    float* Aj = base + (long)(kb * 128) * 512 + jt * 128;
    __shared__ float Ds_[8][132];
    __shared__ float Asj[8][132];
    int tx = tid & 15, ty = tid >> 4;
    int drow = tid >> 1, dkq = (tid & 1) << 2;
    int akr = tid >> 5, acq = (tid & 31) << 2;
    float acc[8][8] = {};
    float4 dv = *(const float4*)(D + (long)drow * 512 + dkq);
    float4 ajv = *(const float4*)(Aj + (long)akr * 512 + acq);
    for (int kc = 0; kc < 128; kc += 8) {
        __syncthreads();
        Ds_[dkq + 0][drow] = dv.x; Ds_[dkq + 1][drow] = dv.y;
        Ds_[dkq + 2][drow] = dv.z; Ds_[dkq + 3][drow] = dv.w;
        *(float4*)&Asj[akr][acq] = ajv;
        float4 dv2, ajv2;
        if (kc + 8 < 128) {
            dv2 = *(const float4*)(D + (long)drow * 512 + kc + 8 + dkq);
            ajv2 = *(const float4*)(Aj + (long)(kc + 8 + akr) * 512 + acq);
        }
        __syncthreads();
        #pragma unroll
        for (int k = 0; k < 8; ++k) {
            float a[8], bv[8];
            *(float4*)&a[0] = *(float4*)&Ds_[k][ty * 8];
            *(float4*)&a[4] = *(float4*)&Ds_[k][ty * 8 + 4];
            *(float4*)&bv[0] = *(float4*)&Asj[k][tx * 8];
            *(float4*)&bv[4] = *(float4*)&Asj[k][tx * 8 + 4];
            #pragma unroll
            for (int i = 0; i < 8; ++i)
                #pragma unroll
                for (int jj = 0; jj < 8; ++jj) acc[i][jj] += a[i] * bv[jj];
        }
        dv = dv2; ajv = ajv2;
    }
    bool dual = (jt == kb + 1);
    float* Fn = Fnext + (long)b * HSTR + (long)(kb * 128) * 128;
    #pragma unroll
    for (int i = 0; i < 8; ++i) {
        float4 o0 = make_float4(acc[i][0], acc[i][1], acc[i][2], acc[i][3]);
        float4 o1 = make_float4(acc[i][4], acc[i][5], acc[i][6], acc[i][7]);
        *(float4*)(Aj + (long)(ty * 8 + i) * 512 + tx * 8) = o0;
        *(float4*)(Aj + (long)(ty * 8 + i) * 512 + tx * 8 + 4) = o1;
        if (dual) {
            *(float4*)(Fn + (long)(ty * 8 + i) * 128 + tx * 8) = o0;
            *(float4*)(Fn + (long)(ty * 8 + i) * 128 + tx * 8 + 4) = o1;
        }
    }
}

// Trailing update: A[i][j] -= F_i @ R_j (j==kb: A[i][kb] = -F_i @ D).
// Dual-writes column kb+1 into Fnext. FUSE: the block computing trailing tile
// (kb+1,kb+1) continues into the in-register inversion of that tile.
template<int FUSE>
__global__ __launch_bounds__(256) void gj_update(float* __restrict__ Lm,
                                                 const float* __restrict__ Fbuf,
                                                 float* __restrict__ Fnext,
                                                 float* __restrict__ logdet, int kb)
{
    __shared__ float sm[FUSE ? 6 : 2][8][132];
    int b = blockIdx.x;
    int it = blockIdx.y;   // 0..2
    int jt = blockIdx.z;   // 0..3
    int ib = it + (it >= kb);
    int tid = threadIdx.x, tx = tid & 15, ty = tid >> 4;
    float* base = Lm + (long)b * LSTR;
    const float* F = Fbuf + (long)b * HSTR + (long)(ib * 128) * 128;
    const float* R = base + (long)(kb * 128) * 512 + jt * 128;
    float* Cb = base + (long)(ib * 128) * 512 + jt * 128;
    float (*Fs)[132] = sm[0];
    float (*Rs)[132] = sm[1];
    int frow = tid >> 1, fkq = (tid & 1) << 2;
    int rkr = tid >> 5, rcq = (tid & 31) << 2;
    float acc[8][8] = {};
    float4 fv = *(const float4*)(F + (long)frow * 128 + fkq);
    float4 rv = *(const float4*)(R + (long)rkr * 512 + rcq);
    for (int kc = 0; kc < 128; kc += 8) {
        __syncthreads();
        Fs[fkq + 0][frow] = fv.x; Fs[fkq + 1][frow] = fv.y;
        Fs[fkq + 2][frow] = fv.z; Fs[fkq + 3][frow] = fv.w;
        *(float4*)&Rs[rkr][rcq] = rv;
        float4 fv2, rv2;
        if (kc + 8 < 128) {
            fv2 = *(const float4*)(F + (long)frow * 128 + kc + 8 + fkq);
            rv2 = *(const float4*)(R + (long)(kc + 8 + rkr) * 512 + rcq);
        }
        __syncthreads();
        #pragma unroll
        for (int k = 0; k < 8; ++k) {
            float a[8], bv[8];
            *(float4*)&a[0] = *(float4*)&Fs[k][ty * 8];
            *(float4*)&a[4] = *(float4*)&Fs[k][ty * 8 + 4];
            *(float4*)&bv[0] = *(float4*)&Rs[k][tx * 8];
            *(float4*)&bv[4] = *(float4*)&Rs[k][tx * 8 + 4];
            #pragma unroll
            for (int i = 0; i < 8; ++i)
                #pragma unroll
                for (int j = 0; j < 8; ++j) acc[i][j] += a[i] * bv[j];
        }
        fv = fv2; rv = rv2;
    }
    if (FUSE && ib == kb + 1 && jt == kb + 1) {
        #pragma unroll
        for (int i = 0; i < 8; ++i) {
            float4 o0 = *(const float4*)(Cb + (long)(ty * 8 + i) * 512 + tx * 8);
            float4 o1 = *(const float4*)(Cb + (long)(ty * 8 + i) * 512 + tx * 8 + 4);
            acc[i][0] = o0.x - acc[i][0]; acc[i][1] = o0.y - acc[i][1];
            acc[i][2] = o0.z - acc[i][2]; acc[i][3] = o0.w - acc[i][3];
            acc[i][4] = o1.x - acc[i][4]; acc[i][5] = o1.y - acc[i][5];
            acc[i][6] = o1.z - acc[i][6]; acc[i][7] = o1.w - acc[i][7];
        }
        float lacc = invert128(acc, tid,
                               (float(*)[8][132])&sm[0],
                               (float(*)[8][132])&sm[FUSE ? 2 : 0],
                               (float(*)[8][132])&sm[FUSE ? 4 : 0]);
        #pragma unroll
        for (int i = 0; i < 8; ++i) {
            *(float4*)(Cb + (long)(ty * 8 + i) * 512 + tx * 8) =
                make_float4(acc[i][0], acc[i][1], acc[i][2], acc[i][3]);
            *(float4*)(Cb + (long)(ty * 8 + i) * 512 + tx * 8 + 4) =
                make_float4(acc[i][4], acc[i][5], acc[i][6], acc[i][7]);
        }
        if (tid == 0) atomicAdd(&logdet[b], lacc);
        return;
    }
    bool dual = (jt == kb + 1);
    float* Fn = Fnext + (long)b * HSTR + (long)(ib * 128) * 128;
    if (jt == kb) {
        #pragma unroll
        for (int i = 0; i < 8; ++i) {
            *(float4*)(Cb + (long)(ty * 8 + i) * 512 + tx * 8) =
                make_float4(-acc[i][0], -acc[i][1], -acc[i][2], -acc[i][3]);
            *(float4*)(Cb + (long)(ty * 8 + i) * 512 + tx * 8 + 4) =
                make_float4(-acc[i][4], -acc[i][5], -acc[i][6], -acc[i][7]);
        }
    } else {
        #pragma unroll
        for (int i = 0; i < 8; ++i) {
            float4 o0 = *(const float4*)(Cb + (long)(ty * 8 + i) * 512 + tx * 8);
            float4 o1 = *(const float4*)(Cb + (long)(ty * 8 + i) * 512 + tx * 8 + 4);
            o0 = make_float4(o0.x - acc[i][0], o0.y - acc[i][1],
                             o0.z - acc[i][2], o0.w - acc[i][3]);
            o1 = make_float4(o1.x - acc[i][4], o1.y - acc[i][5],
                             o1.z - acc[i][6], o1.w - acc[i][7]);
            *(float4*)(Cb + (long)(ty * 8 + i) * 512 + tx * 8) = o0;
            *(float4*)(Cb + (long)(ty * 8 + i) * 512 + tx * 8 + 4) = o1;
            if (dual) {
                *(float4*)(Fn + (long)(ty * 8 + i) * 128 + tx * 8) = o0;
                *(float4*)(Fn + (long)(ty * 8 + i) * 128 + tx * 8 + 4) = o1;
            }
        }
    }
}

// --------------------------- marginals Y + entropy partials -----------------
__global__ __launch_bounds__(256) void y_k(const float* __restrict__ sc,
                                           const float* __restrict__ Binv,
                                           const int* __restrict__ len,
                                           const unsigned* __restrict__ cu,
                                           float* __restrict__ Y,
                                           float* __restrict__ Ssum)
{
    int b = blockIdx.x;
    int ht = blockIdx.y >> 3, mt = blockIdx.y & 7;
    int h0 = ht * 64, m0 = mt * 64;
    int tid = threadIdx.x;
    int L = len[b];
    float c = mono2f(cu[b]);
    const float* S = sc + (long)b * SSTR;
    const float* Bi = Binv + (long)b * LSTR;
    float* Yb = Y + (long)b * SSTR;
    __shared__ float Bs[64][65];
    __shared__ float Ds[64], C0s[64];
    {
        int hh = tid & 63, m4 = tid >> 6;
        int col = h0 + hh - 1;
        for (int mm = m4; mm < 64; mm += 4) {
            int row = m0 + mm - 1;
            Bs[mm][hh] = (row >= 0 && col >= 0) ? Bi[(long)row * 512 + col] : 0.f;
        }
    }
    if (tid < 64) {
        int row = m0 + tid - 1;
        Ds[tid] = (row >= 0) ? Bi[(long)row * 512 + row] : 0.f;
    } else if (tid < 128) {
        int mm = tid - 64, row = m0 + mm - 1;
        C0s[mm] = (row >= 0) ? Bi[(long)row * 512] : 0.f;
    }
    __syncthreads();
    int mm = tid & 63, hq = tid >> 6;
    int m = m0 + mm;
    float lsum = 0.f;
    bool mvalid = (m >= 1 && m <= L);
    float dterm = (m >= 2) ? Ds[mm] : 0.f;
    #pragma unroll
    for (int hi = 0; hi < 16; ++hi) {
        int hh = hq * 16 + hi;
        int h = h0 + hh;
        float s = S[(long)h * NN_ + m];
        float y = 0.f;
        if (mvalid && h <= L && h != m) {
            float a = expf(s - c);
            float g;
            if (h == 0) g = C0s[mm] + dterm;
            else g = dterm - ((h >= 2) ? Bs[mm][hh] : 0.f);
            y = a * g;
        }
        Yb[(long)h * NN_ + m] = y;
        lsum += y * s;
    }
    __shared__ float red[256];
    red[tid] = lsum; __syncthreads();
    for (int off = 128; off; off >>= 1) {
        if (tid < off) red[tid] += red[tid + off];
        __syncthreads();
    }
    if (tid == 0) atomicAdd(&Ssum[b], red[0]);
}

// finalize + re-zero accumulators for the next iteration
__global__ void fin_k(const int* __restrict__ len, unsigned* __restrict__ cu,
                      float* __restrict__ logdet, float* __restrict__ Ssum,
                      float* __restrict__ outLogZ, float* __restrict__ outEntr)
{
    int b = threadIdx.x;
    if (b < 32) {
        float c = mono2f(cu[b]);
        float lz = logdet[b] + (float)len[b] * c;
        outLogZ[b] = lz;
        outEntr[b] = lz - Ssum[b];
        cu[b] = 0u;
        logdet[b] = 0.f;
        Ssum[b] = 0.f;
    }
}

// ---------------------------------------------------------------------------
extern "C" void kernel_launch(void* const* d_in, const int* in_sizes, int n_in,
                              void* d_out, int out_size, void* d_ws, size_t ws_size,
                              hipStream_t stream)
{
    const float* Xh = (const float*)d_in[0];
    const float* Xm = (const float*)d_in[1];
    const int*   len = (const int*)d_in[2];
    const float* Wh = (const float*)d_in[3];
    const float* bh = (const float*)d_in[4];
    const float* Wm = (const float*)d_in[5];
    const float* bm = (const float*)d_in[6];
    const float* V  = (const float*)d_in[7];

    float* ws = (float*)d_ws;
    constexpr long U = 2097152;           // 32*512*128
    float* H0 = ws;
    float* M0 = ws + U;
    float* Ha = ws + 2 * U;
    float* Ma = ws + 3 * U;
    float* Hb = ws + 4 * U;
    float* Mb = ws + 5 * U;
    float* T1 = ws + 6 * U;               // P = H@V (live across GJ!)
    float* Yt = ws + 7 * U;               // Q scratch (feedback) / Fbuf ping (GJ)
    float* Lm = ws + 8 * U;               // 32 x 512 x 512
    float* cs = ws + 12 * U;              // colsum 32*512
    float* scal = ws + 12 * U + 16384;    // c_u[32] | logdet[32] | Ssum[32]
    unsigned* cu = (unsigned*)scal;
    float* logdet = scal + 32;
    float* Ssum = scal + 64;

    float* Sout = (float*)d_out;                        // scores  [32,512,512]
    float* outLogZ = (float*)d_out + 8388608;           // logZ    [32]
    float* Yout = (float*)d_out + 8388640;              // Y       [32,512,512]
    float* outEntr = (float*)d_out + 8388640 + 8388608; // entr    [32]

    zero_scal<<<1, 96, 0, stream>>>(scal);

    // H0 = Xh@Wh^T + bh ; H = relu(H0)   (and same for M)
    gemm64<0,1,1><<<dim3(256, 2, 1), 256, 0, stream>>>(
        Xh, Wh, Ha, bh, H0, 16384, DH, DIN, 0, 0, 0, 0);
    gemm64<0,1,1><<<dim3(256, 2, 1), 256, 0, stream>>>(
        Xm, Wm, Ma, bm, M0, 16384, DH, DIN, 0, 0, 0, 0);

    float* Hc = Ha; float* Mc = Ma; float* Hn = Hb; float* Mn = Mb;
    for (int t = 0; t < NITER; ++t) {
        if (t > 0) {
            // Q = Mc @ V^T (Yt); Hn = relu(H0 + Y@Q); Mn = relu(M0 + Y^T@P)
            gemm64<0,1,0><<<dim3(8,2,BB),256,0,stream>>>(
                Mc, V, Yt, nullptr, nullptr, 512, DH, DH, HSTR, 0, HSTR, 0);
            gemm64<0,0,2><<<dim3(8,2,BB),256,0,stream>>>(
                Yout, Yt, Hn, H0, nullptr, 512, DH, 512, SSTR, HSTR, HSTR, HSTR);
            gemm64<1,0,2><<<dim3(8,2,BB),256,0,stream>>>(
                Yout, T1, Mn, M0, nullptr, 512, DH, 512, SSTR, HSTR, HSTR, HSTR);
            { float* tmp = Hc; Hc = Hn; Hn = tmp; }
            { float* tmp = Mc; Mc = Mn; Mn = tmp; }
        }
        // P = Hc @ V (T1, persists to next feedback); scores = P @ Mc^T
        gemm64<0,0,0><<<dim3(8,2,BB),256,0,stream>>>(
            Hc, V, T1, nullptr, nullptr, 512, DH, DH, HSTR, 0, HSTR, 0);
        score_gemm<<<dim3(4,4,BB),256,0,stream>>>(T1, Mc, Sout, len, cu);

        // lean colsum, then build (8 rows/block) + fused diag-0 inversion
        colsum_k<<<dim3(BB,8),256,0,stream>>>(Sout, len, cu, cs);
        build_rows<<<dim3(BB,65),256,0,stream>>>(Sout, len, cu, cs, Lm, Yt, logdet);

        // Fbuf ping-pong: even kb reads Yt, writes Hn (dead during GJ); odd flips
        float* Fbufs[2] = {Yt, Hn};
        for (int kb = 0; kb < 4; ++kb) {
            float* Fcur  = Fbufs[kb & 1];
            float* Fnext = Fbufs[(kb + 1) & 1];
            gj_panel<<<dim3(BB,3),256,0,stream>>>(Lm, Fnext, kb);
            if (kb < 3)
                gj_update<1><<<dim3(BB,3,4),256,0,stream>>>(Lm, Fcur, Fnext, logdet, kb);
            else
                gj_update<0><<<dim3(BB,3,4),256,0,stream>>>(Lm, Fcur, Fnext, logdet, kb);
        }
        y_k<<<dim3(BB,64),256,0,stream>>>(Sout, Lm, len, cu, Yout, Ssum);
        fin_k<<<1,32,0,stream>>>(len, cu, logdet, Ssum, outLogZ, outEntr);
    }
}